// Round 11
// baseline (300.594 us; speedup 1.0000x reference)
//
#include <hip/hip_runtime.h>

// mean( (scale*(norms - label))^2 ), scale = 5 if label==1, 3 if label==2, else 1.
// B*S = 4096*8192 = 33,554,432 elements. 268 MB logical traffic.
//
// History: R4 (VGPR=16, grid2048) 101us; R8 (8-deep batch, VGPR=44, grid4096)
// 101us; R10 (+launch_bounds(256,4), VGPR still 44) 101us. All = 2.64 TB/s
// logical. MLP axis exhausted — in-flight bytes per CU are Little's-law
// sufficient in every config. Untested axis: sustained TLP. Prior grids were
// <= exact capacity (tail-drain, occ 42-60%). This round mimics the 6.29 TB/s
// float4-copy shape: plain interleaved grid-stride, low VGPR, grid 8192 so
// residency stays full; 2-way ILP; one atomic per block (8192 total).

#define BLOCK 256

__device__ __forceinline__ float sq_term(float n, int l) {
    float s = (l == 1) ? 5.0f : ((l == 2) ? 3.0f : 1.0f);
    float d = s * (n - (float)l);
    return d * d;
}

__global__ void buff_loss_kernel(
        const float* __restrict__ norms,
        const int*   __restrict__ labs,
        float*       __restrict__ out,
        int nvec,            // number of float4/int4 groups
        float inv_n) {
    const float4* __restrict__ n4 = reinterpret_cast<const float4*>(norms);
    const int4*   __restrict__ l4 = reinterpret_cast<const int4*>(labs);

    float acc0 = 0.0f, acc1 = 0.0f;
    const int tid    = blockIdx.x * blockDim.x + threadIdx.x;
    const int stride = gridDim.x * blockDim.x;

    // Plain interleaved grid-stride, 2 independent load-pairs per iteration.
    int i = tid;
    for (; i + stride < nvec; i += 2 * stride) {
        float4 na = n4[i];
        int4   la = l4[i];
        float4 nb = n4[i + stride];
        int4   lb = l4[i + stride];
        acc0 += sq_term(na.x, la.x) + sq_term(na.y, la.y)
              + sq_term(na.z, la.z) + sq_term(na.w, la.w);
        acc1 += sq_term(nb.x, lb.x) + sq_term(nb.y, lb.y)
              + sq_term(nb.z, lb.z) + sq_term(nb.w, lb.w);
    }
    if (i < nvec) {
        float4 n = n4[i];
        int4   l = l4[i];
        acc0 += sq_term(n.x, l.x) + sq_term(n.y, l.y)
              + sq_term(n.z, l.z) + sq_term(n.w, l.w);
    }

    float acc = acc0 + acc1;

    // wave64 shuffle reduction
    #pragma unroll
    for (int off = 32; off > 0; off >>= 1)
        acc += __shfl_down(acc, off, 64);

    __shared__ float smem[BLOCK / 64];
    int lane = threadIdx.x & 63;
    int wid  = threadIdx.x >> 6;
    if (lane == 0) smem[wid] = acc;
    __syncthreads();

    if (threadIdx.x == 0) {
        float t = (smem[0] + smem[1]) + (smem[2] + smem[3]);
        atomicAdd(out, t * inv_n);
    }
}

extern "C" void kernel_launch(void* const* d_in, const int* in_sizes, int n_in,
                              void* d_out, int out_size, void* d_ws, size_t ws_size,
                              hipStream_t stream) {
    const float* norms = (const float*)d_in[0];
    const int*   labs  = (const int*)d_in[1];
    float*       out   = (float*)d_out;

    int n    = in_sizes[0];          // 33,554,432 (divisible by 4)
    int nvec = n >> 2;               // float4 groups = 8,388,608
    float inv_n = 1.0f / (float)n;

    // d_out is re-poisoned to 0xAA before every timed call — zero it first.
    hipMemsetAsync(d_out, 0, sizeof(float), stream);

    // Wide grid: 8192 blocks (4 float4-pairs per thread) keeps all CUs at
    // full residency with continuous block replacement (no drain tail).
    int grid = 8192;
    int need = (nvec + BLOCK - 1) / BLOCK;
    if (grid > need) grid = need;

    buff_loss_kernel<<<grid, BLOCK, 0, stream>>>(norms, labs, out, nvec, inv_n);
}

// Round 12
// 258.995 us; speedup vs baseline: 1.1606x; 1.1606x over previous
//
#include <hip/hip_runtime.h>

// mean( (scale*(norms - label))^2 ), scale = 5 if label==1, 3 if label==2, else 1.
// B*S = 4096*8192 = 33,554,432 elements. 268 MB logical read traffic.
//
// R4 (grid2048, VGPR16): 101us. R8 (8-deep batch, VGPR44): 101us.
// R10 (+launch_bounds(256,4): compiler ignored, VGPR44): 101us.
// R11 (grid8192 wide, occ 65%): 122us. All ~2.65 TB/s logical.
// KEY EVIDENCE: dispatches with ~zero HBM fetch (fully L3-served) take the
// SAME 101us as ones fetching 134MB from HBM -> HBM BW is not the limiter;
// the shared L3/fabric path is. Working set 268MB > L3 256MB -> every read
// causes L3 fill + evict (internal write traffic ~2x reads) = thrash.
// R12: single change vs R4 -> nontemporal loads (global_load_dwordx4 nt,
// no L2/L3 allocation). Streamed-once data never re-read within a dispatch.

#define BLOCK 256

typedef float vf4 __attribute__((ext_vector_type(4)));
typedef int   vi4 __attribute__((ext_vector_type(4)));

__device__ __forceinline__ float sq_term(float n, int l) {
    float s = (l == 1) ? 5.0f : ((l == 2) ? 3.0f : 1.0f);
    float d = s * (n - (float)l);
    return d * d;
}

__global__ __launch_bounds__(BLOCK) void buff_loss_kernel(
        const float* __restrict__ norms,
        const int*   __restrict__ labs,
        float*       __restrict__ out,
        int nvec,            // number of float4/int4 groups
        float inv_n) {
    const vf4* __restrict__ n4 = reinterpret_cast<const vf4*>(norms);
    const vi4* __restrict__ l4 = reinterpret_cast<const vi4*>(labs);

    float acc0 = 0.0f, acc1 = 0.0f;
    const int tid    = blockIdx.x * blockDim.x + threadIdx.x;
    const int stride = gridDim.x * blockDim.x;

    // Same shape as the R4 101us baseline; ONLY the load instruction changes:
    // nontemporal (nt) -> bypass L2/L3 allocation, kill cache-thrash traffic.
    int i = tid;
    for (; i + stride < nvec; i += 2 * stride) {
        vf4 na = __builtin_nontemporal_load(n4 + i);
        vi4 la = __builtin_nontemporal_load(l4 + i);
        vf4 nb = __builtin_nontemporal_load(n4 + i + stride);
        vi4 lb = __builtin_nontemporal_load(l4 + i + stride);
        acc0 += sq_term(na.x, la.x) + sq_term(na.y, la.y)
              + sq_term(na.z, la.z) + sq_term(na.w, la.w);
        acc1 += sq_term(nb.x, lb.x) + sq_term(nb.y, lb.y)
              + sq_term(nb.z, lb.z) + sq_term(nb.w, lb.w);
    }
    if (i < nvec) {
        vf4 n = __builtin_nontemporal_load(n4 + i);
        vi4 l = __builtin_nontemporal_load(l4 + i);
        acc0 += sq_term(n.x, l.x) + sq_term(n.y, l.y)
              + sq_term(n.z, l.z) + sq_term(n.w, l.w);
    }

    float acc = acc0 + acc1;

    // wave64 shuffle reduction
    #pragma unroll
    for (int off = 32; off > 0; off >>= 1)
        acc += __shfl_down(acc, off, 64);

    __shared__ float smem[BLOCK / 64];
    int lane = threadIdx.x & 63;
    int wid  = threadIdx.x >> 6;
    if (lane == 0) smem[wid] = acc;
    __syncthreads();

    if (threadIdx.x == 0) {
        float t = (smem[0] + smem[1]) + (smem[2] + smem[3]);
        atomicAdd(out, t * inv_n);
    }
}

extern "C" void kernel_launch(void* const* d_in, const int* in_sizes, int n_in,
                              void* d_out, int out_size, void* d_ws, size_t ws_size,
                              hipStream_t stream) {
    const float* norms = (const float*)d_in[0];
    const int*   labs  = (const int*)d_in[1];
    float*       out   = (float*)d_out;

    int n    = in_sizes[0];          // 33,554,432 (divisible by 4)
    int nvec = n >> 2;               // float4 groups = 8,388,608
    float inv_n = 1.0f / (float)n;

    // d_out is re-poisoned to 0xAA before every timed call — zero it first.
    hipMemsetAsync(d_out, 0, sizeof(float), stream);

    const int block = BLOCK;
    int grid = (nvec + block - 1) / block;
    if (grid > 2048) grid = 2048;

    buff_loss_kernel<<<grid, block, 0, stream>>>(norms, labs, out, nvec, inv_n);
}

// Round 13
// 256.067 us; speedup vs baseline: 1.1739x; 1.0114x over previous
//
#include <hip/hip_runtime.h>

// mean( (scale*(norms - label))^2 ), scale = 5 if label==1, 3 if label==2, else 1.
// B*S = 4096*8192 = 33,554,432 elements. 268 MB logical read traffic.
//
// R4/R8/R10: cached loads, all pinned at 101us (~2.65 TB/s logical) whether
// data came from HBM or L3 -> cache-path (L3 fill+evict thrash; 268MB > 256MB
// L3) was the limiter, not HBM.
// R12: nontemporal loads (nt, no L2/L3 allocation) -> kernel dropped below
// the 78us harness fill ops (was 101us); headline 277->259us. Harness fills
// run at 6.8 TB/s (86% peak) -> memory system has headroom.
// R13: keep nt; deepen MLP 2->4-way stride unroll (8 nt loads = 128B in
// flight per thread) to cover HBM latency now that every read misses cache.

#define BLOCK 256

typedef float vf4 __attribute__((ext_vector_type(4)));
typedef int   vi4 __attribute__((ext_vector_type(4)));

__device__ __forceinline__ float sq_term(float n, int l) {
    float s = (l == 1) ? 5.0f : ((l == 2) ? 3.0f : 1.0f);
    float d = s * (n - (float)l);
    return d * d;
}

__global__ __launch_bounds__(BLOCK) void buff_loss_kernel(
        const float* __restrict__ norms,
        const int*   __restrict__ labs,
        float*       __restrict__ out,
        int nvec,            // number of float4/int4 groups
        float inv_n) {
    const vf4* __restrict__ n4 = reinterpret_cast<const vf4*>(norms);
    const vi4* __restrict__ l4 = reinterpret_cast<const vi4*>(labs);

    float acc0 = 0.0f, acc1 = 0.0f, acc2 = 0.0f, acc3 = 0.0f;
    const int tid    = blockIdx.x * blockDim.x + threadIdx.x;
    const int stride = gridDim.x * blockDim.x;

    // 4-way stride unroll: 8 independent nt loads issued before any use.
    int i = tid;
    for (; i + 3 * stride < nvec; i += 4 * stride) {
        vf4 na = __builtin_nontemporal_load(n4 + i);
        vf4 nb = __builtin_nontemporal_load(n4 + i + stride);
        vf4 nc = __builtin_nontemporal_load(n4 + i + 2 * stride);
        vf4 nd = __builtin_nontemporal_load(n4 + i + 3 * stride);
        vi4 la = __builtin_nontemporal_load(l4 + i);
        vi4 lb = __builtin_nontemporal_load(l4 + i + stride);
        vi4 lc = __builtin_nontemporal_load(l4 + i + 2 * stride);
        vi4 ld = __builtin_nontemporal_load(l4 + i + 3 * stride);
        acc0 += sq_term(na.x, la.x) + sq_term(na.y, la.y)
              + sq_term(na.z, la.z) + sq_term(na.w, la.w);
        acc1 += sq_term(nb.x, lb.x) + sq_term(nb.y, lb.y)
              + sq_term(nb.z, lb.z) + sq_term(nb.w, lb.w);
        acc2 += sq_term(nc.x, lc.x) + sq_term(nc.y, lc.y)
              + sq_term(nc.z, lc.z) + sq_term(nc.w, lc.w);
        acc3 += sq_term(nd.x, ld.x) + sq_term(nd.y, ld.y)
              + sq_term(nd.z, ld.z) + sq_term(nd.w, ld.w);
    }
    for (; i < nvec; i += stride) {
        vf4 n = __builtin_nontemporal_load(n4 + i);
        vi4 l = __builtin_nontemporal_load(l4 + i);
        acc0 += sq_term(n.x, l.x) + sq_term(n.y, l.y)
              + sq_term(n.z, l.z) + sq_term(n.w, l.w);
    }

    float acc = (acc0 + acc1) + (acc2 + acc3);

    // wave64 shuffle reduction
    #pragma unroll
    for (int off = 32; off > 0; off >>= 1)
        acc += __shfl_down(acc, off, 64);

    __shared__ float smem[BLOCK / 64];
    int lane = threadIdx.x & 63;
    int wid  = threadIdx.x >> 6;
    if (lane == 0) smem[wid] = acc;
    __syncthreads();

    if (threadIdx.x == 0) {
        float t = (smem[0] + smem[1]) + (smem[2] + smem[3]);
        atomicAdd(out, t * inv_n);
    }
}

extern "C" void kernel_launch(void* const* d_in, const int* in_sizes, int n_in,
                              void* d_out, int out_size, void* d_ws, size_t ws_size,
                              hipStream_t stream) {
    const float* norms = (const float*)d_in[0];
    const int*   labs  = (const int*)d_in[1];
    float*       out   = (float*)d_out;

    int n    = in_sizes[0];          // 33,554,432 (divisible by 4)
    int nvec = n >> 2;               // float4 groups = 8,388,608
    float inv_n = 1.0f / (float)n;

    // d_out is re-poisoned to 0xAA before every timed call — zero it first.
    hipMemsetAsync(d_out, 0, sizeof(float), stream);

    const int block = BLOCK;
    int grid = (nvec + block - 1) / block;
    if (grid > 2048) grid = 2048;

    buff_loss_kernel<<<grid, block, 0, stream>>>(norms, labs, out, nvec, inv_n);
}